// Round 1
// baseline (157.538 us; speedup 1.0000x reference)
//
#include <hip/hip_runtime.h>

// Segment attention pooling, MI355X (gfx950).
// Pipeline: convW (fp32->bf16) ; segscan (cumsum of SEP) ;
//           score_gemm (bf16 MFMA GEMM + fused tanh*v epilogue) ;
//           pool (per-(b,m) softmax + weighted sum of hidden rows).

#define SEP_ID 102
#define Bn 64
#define Sn 512
#define Hn 768
#define Mn 21
#define BS (Bn * Sn)   // 32768 rows

typedef __attribute__((ext_vector_type(8))) short bf16x8;
typedef __attribute__((ext_vector_type(4))) float f32x4;

__device__ inline unsigned short f2bf(float x) {
  unsigned int u = __builtin_bit_cast(unsigned int, x);
  u += 0x7fffu + ((u >> 16) & 1u);   // RNE
  return (unsigned short)(u >> 16);
}

// ---------------- kernel 1: convert W (HxH fp32 -> bf16, same [k][h] layout)
__global__ void convw_kernel(const float* __restrict__ W, unsigned short* __restrict__ WB) {
  int i = (blockIdx.x * 256 + threadIdx.x) * 4;   // 589824 floats, exact
  float4 x = *reinterpret_cast<const float4*>(&W[i]);
  ushort4 u;
  u.x = f2bf(x.x); u.y = f2bf(x.y); u.z = f2bf(x.z); u.w = f2bf(x.w);
  *reinterpret_cast<ushort4*>(&WB[i]) = u;
}

// ---------------- kernel 2: per-batch segment scan
// segv[b][s] = segment id if position is valid, else 0xFF. nsep[b] = #separators.
__global__ void segscan_kernel(const int* __restrict__ ids,
                               unsigned char* __restrict__ segv,
                               int* __restrict__ nsep) {
  int b = blockIdx.x;
  int s = threadIdx.x;            // 512 threads
  __shared__ int cs[Sn];
  int sep = (ids[b * Sn + s] == SEP_ID) ? 1 : 0;
  cs[s] = sep;
  __syncthreads();
  for (int off = 1; off < Sn; off <<= 1) {
    int add = (s >= off) ? cs[s - off] : 0;
    __syncthreads();
    cs[s] += add;
    __syncthreads();
  }
  int csum = cs[s];
  int nb = cs[Sn - 1];
  int seg = csum - sep;
  bool valid = (!sep) && (s >= 1) && (seg < nb) && (seg < Mn);
  segv[b * Sn + s] = valid ? (unsigned char)seg : (unsigned char)0xFF;
  if (s == 0) nsep[b] = nb;
}

// ---------------- kernel 3: scores[b,s] = v . tanh(hidden @ W^T + bias)
// GEMM M=32768, N=768, K=768. Block: 256 thr (4 waves 2Mx2N), BM=64, BN=128,
// 6 n-tiles looped in-block, K in 24 steps of 32. bf16 MFMA 16x16x32.
__global__ __launch_bounds__(256) void score_gemm_kernel(
    const float* __restrict__ hid, const unsigned short* __restrict__ WB,
    const float* __restrict__ bbias, const float* __restrict__ vvec,
    float* __restrict__ scores) {
  __shared__ unsigned short As[64 * 32];    // [row][32k], 16B slots rotated
  __shared__ unsigned short Bs[128 * 32];   // [ncol][32k], 16B slots rotated
  __shared__ float vLds[Hn];
  __shared__ float bLds[Hn];
  __shared__ float scpart[2][64];

  int t = threadIdx.x;
  int rowBase = blockIdx.x * 64;
  for (int i = t; i < Hn; i += 256) { vLds[i] = vvec[i]; bLds[i] = bbias[i]; }

  int wid = t >> 6, lane = t & 63;
  int waveM = wid >> 1, waveN = wid & 1;    // 2x2 waves, each 32(M) x 64(N)
  int l15 = lane & 15, l4 = lane >> 4;

  float sc[2][4] = {};                      // per-lane score partials [mi][reg]

  for (int nt = 0; nt < 6; ++nt) {
    int ncol0 = nt * 128;
    f32x4 acc[2][4];
#pragma unroll
    for (int mi = 0; mi < 2; ++mi)
#pragma unroll
      for (int ni = 0; ni < 4; ++ni) acc[mi][ni] = (f32x4){0.f, 0.f, 0.f, 0.f};

    for (int kk = 0; kk < 24; ++kk) {
      int kbase = kk * 32;
      __syncthreads();  // previous iter's frag reads done before overwrite
      // ---- stage A: 64 rows x 32 k, fp32 -> bf16 on the fly
#pragma unroll
      for (int i = 0; i < 2; ++i) {
        int f = i * 256 + t;                 // 0..511 float4 units
        int row = f >> 3;                    // 0..63
        int k0 = (f & 7) * 4;                // 0,4,...,28
        float4 x = *reinterpret_cast<const float4*>(
            &hid[(size_t)(rowBase + row) * Hn + kbase + k0]);
        ushort4 u;
        u.x = f2bf(x.x); u.y = f2bf(x.y); u.z = f2bf(x.z); u.w = f2bf(x.w);
        int kq = k0 >> 3;
        int slot = (kq + (row >> 1)) & 3;    // bank-conflict swizzle
        int off = row * 32 + slot * 8 + (k0 & 7);
        *reinterpret_cast<ushort4*>(&As[off]) = u;
      }
      // ---- stage B: 128 W-rows x 32 k, bf16 16B copies
#pragma unroll
      for (int i = 0; i < 2; ++i) {
        int g = i * 256 + t;                 // 0..511 16B units
        int nl = g >> 2;                     // 0..127
        int kq = g & 3;
        uint4 x = *reinterpret_cast<const uint4*>(
            &WB[(size_t)(ncol0 + nl) * Hn + kbase + kq * 8]);
        int slot = (kq + (nl >> 1)) & 3;
        *reinterpret_cast<uint4*>(&Bs[nl * 32 + slot * 8]) = x;
      }
      __syncthreads();
      // ---- frags + MFMA
      bf16x8 af[2], bfg[4];
#pragma unroll
      for (int mi = 0; mi < 2; ++mi) {
        int r = waveM * 32 + mi * 16 + l15;
        int slot = (l4 + (r >> 1)) & 3;
        af[mi] = *reinterpret_cast<const bf16x8*>(&As[r * 32 + slot * 8]);
      }
#pragma unroll
      for (int ni = 0; ni < 4; ++ni) {
        int c = waveN * 64 + ni * 16 + l15;
        int slot = (l4 + (c >> 1)) & 3;
        bfg[ni] = *reinterpret_cast<const bf16x8*>(&Bs[c * 32 + slot * 8]);
      }
#pragma unroll
      for (int mi = 0; mi < 2; ++mi)
#pragma unroll
        for (int ni = 0; ni < 4; ++ni)
          acc[mi][ni] = __builtin_amdgcn_mfma_f32_16x16x32_bf16(
              af[mi], bfg[ni], acc[mi][ni], 0, 0, 0);
    }
    // ---- fused epilogue: tanh(pre + b) * v, reduce over this n-tile's cols
#pragma unroll
    for (int mi = 0; mi < 2; ++mi)
#pragma unroll
      for (int ni = 0; ni < 4; ++ni) {
        int col = ncol0 + waveN * 64 + ni * 16 + l15;
        float vv = vLds[col];
        float bb = bLds[col];
#pragma unroll
        for (int r = 0; r < 4; ++r)
          sc[mi][r] += tanhf(acc[mi][ni][r] + bb) * vv;
      }
  }
  // reduce the 16 cols held across lane bits 0..3
#pragma unroll
  for (int off = 1; off < 16; off <<= 1)
#pragma unroll
    for (int mi = 0; mi < 2; ++mi)
#pragma unroll
      for (int r = 0; r < 4; ++r)
        sc[mi][r] += __shfl_xor(sc[mi][r], off, 64);
  if (l15 == 0) {
#pragma unroll
    for (int mi = 0; mi < 2; ++mi)
#pragma unroll
      for (int r = 0; r < 4; ++r)
        scpart[waveN][waveM * 32 + mi * 16 + l4 * 4 + r] = sc[mi][r];
  }
  __syncthreads();
  if (t < 64) scores[rowBase + t] = scpart[0][t] + scpart[1][t];
}

// ---------------- kernel 4: per-(b,m) segment softmax + weighted pooling
__global__ __launch_bounds__(256) void pool_kernel(
    const float* __restrict__ hid, const float* __restrict__ scores,
    const unsigned char* __restrict__ segv, const int* __restrict__ nsep,
    float* __restrict__ out) {
  int bm = blockIdx.x;
  int b = bm / Mn, m = bm % Mn;
  int t = threadIdx.x;                      // 256 threads
  __shared__ float wLds[Sn];
  __shared__ float red[256];
  __shared__ int ired[256];
  const float NEG = -1e30f;

  int base = b * Sn;
  unsigned char mg = (unsigned char)m;
  unsigned char g0 = segv[base + t], g1 = segv[base + 256 + t];
  bool v0 = (g0 == mg), v1 = (g1 == mg);
  float s0 = v0 ? scores[base + t] : NEG;
  float s1 = v1 ? scores[base + 256 + t] : NEG;

  // block max
  red[t] = fmaxf(s0, s1);
  __syncthreads();
  for (int o = 128; o > 0; o >>= 1) {
    if (t < o) red[t] = fmaxf(red[t], red[t + o]);
    __syncthreads();
  }
  float gmax = red[0];
  __syncthreads();

  size_t obase = (size_t)bm * Hn;
  if (gmax <= -0.5e30f) {                    // empty segment
    int nb = nsep[b];
    float a0 = 0.f, a1 = 0.f, a2 = 0.f;
    if (m == 0 && nb == 0) {
      const float* hp = hid + (size_t)base * Hn;
      a0 = hp[t]; a1 = hp[t + 256]; a2 = hp[t + 512];
    }
    out[obase + t] = a0; out[obase + 256 + t] = a1; out[obase + 512 + t] = a2;
    return;
  }

  float e0 = v0 ? expf(s0 - gmax) : 0.f;
  float e1 = v1 ? expf(s1 - gmax) : 0.f;
  red[t] = e0 + e1;
  __syncthreads();
  for (int o = 128; o > 0; o >>= 1) {
    if (t < o) red[t] += red[t + o];
    __syncthreads();
  }
  float inv = 1.f / red[0];
  __syncthreads();
  wLds[t] = e0 * inv;
  wLds[256 + t] = e1 * inv;

  // segment position range (segments are contiguous runs)
  ired[t] = min(v0 ? t : 0x7fffffff, v1 ? (256 + t) : 0x7fffffff);
  __syncthreads();
  for (int o = 128; o > 0; o >>= 1) {
    if (t < o) ired[t] = min(ired[t], ired[t + o]);
    __syncthreads();
  }
  int start = ired[0];
  __syncthreads();
  ired[t] = max(v0 ? t : -1, v1 ? (256 + t) : -1);
  __syncthreads();
  for (int o = 128; o > 0; o >>= 1) {
    if (t < o) ired[t] = max(ired[t], ired[t + o]);
    __syncthreads();
  }
  int end = ired[0];
  __syncthreads();

  float a0 = 0.f, a1 = 0.f, a2 = 0.f;
  for (int s = start; s <= end; ++s) {
    float w = wLds[s];
    if (w != 0.f) {
      const float* hp = hid + (size_t)(base + s) * Hn;
      a0 += w * hp[t];
      a1 += w * hp[t + 256];
      a2 += w * hp[t + 512];
    }
  }
  out[obase + t] = a0;
  out[obase + 256 + t] = a1;
  out[obase + 512 + t] = a2;
}

// ---------------- launch
extern "C" void kernel_launch(void* const* d_in, const int* in_sizes, int n_in,
                              void* d_out, int out_size, void* d_ws, size_t ws_size,
                              hipStream_t stream) {
  const float* hidden = (const float*)d_in[0];
  const int* ids      = (const int*)d_in[1];
  const float* W      = (const float*)d_in[2];
  const float* bbias  = (const float*)d_in[3];
  const float* vvec   = (const float*)d_in[4];

  char* ws = (char*)d_ws;
  unsigned short* WB   = (unsigned short*)(ws);            // 1,179,648 B
  float* scores        = (float*)(ws + 1179648);           //   131,072 B
  unsigned char* segv  = (unsigned char*)(ws + 1310720);   //    32,768 B
  int* nsep            = (int*)(ws + 1343488);             //       256 B

  convw_kernel<<<576, 256, 0, stream>>>(W, WB);
  segscan_kernel<<<Bn, Sn, 0, stream>>>(ids, segv, nsep);
  score_gemm_kernel<<<BS / 64, 256, 0, stream>>>(hidden, WB, bbias, vvec, scores);
  pool_kernel<<<Bn * Mn, 256, 0, stream>>>(hidden, scores, segv, nsep, (float*)d_out);
}

// Round 2
// 106.961 us; speedup vs baseline: 1.4729x; 1.4729x over previous
//
#include <hip/hip_runtime.h>

// Segment attention pooling, MI355X (gfx950).
// Pipeline: convW (fp32->bf16) ; segscan (cumsum of SEP) ;
//           score_gemm (bf16 MFMA, single-pass N, B-frags direct from L2) ;
//           pool (per-(b,m) softmax + weighted sum of hidden rows).

#define SEP_ID 102
#define Bn 64
#define Sn 512
#define Hn 768
#define Mn 21
#define BS (Bn * Sn)   // 32768 rows

typedef __attribute__((ext_vector_type(8))) short bf16x8;
typedef __attribute__((ext_vector_type(4))) float f32x4;

__device__ inline unsigned short f2bf(float x) {
  unsigned int u = __builtin_bit_cast(unsigned int, x);
  u += 0x7fffu + ((u >> 16) & 1u);   // RNE
  return (unsigned short)(u >> 16);
}

__device__ inline float tanh_fast(float x) {
  // tanh(x) = 1 - 2/(exp(2x)+1); exp via v_exp_f32 (2^y), rcp via v_rcp_f32.
  // Saturates correctly for |x| large (inf -> rcp 0 -> 1; 0 -> -1).
  float e = __builtin_amdgcn_exp2f(x * 2.885390081777927f); // 2*log2(e)
  return 1.f - 2.f * __builtin_amdgcn_rcpf(e + 1.f);
}

// ---------------- kernel 1: convert W (HxH fp32 -> bf16, same [n][k] layout)
__global__ void convw_kernel(const float* __restrict__ W, unsigned short* __restrict__ WB) {
  int i = (blockIdx.x * 256 + threadIdx.x) * 4;   // 589824 floats, exact
  float4 x = *reinterpret_cast<const float4*>(&W[i]);
  ushort4 u;
  u.x = f2bf(x.x); u.y = f2bf(x.y); u.z = f2bf(x.z); u.w = f2bf(x.w);
  *reinterpret_cast<ushort4*>(&WB[i]) = u;
}

// ---------------- kernel 2: per-batch segment scan
__global__ void segscan_kernel(const int* __restrict__ ids,
                               unsigned char* __restrict__ segv,
                               int* __restrict__ nsep) {
  int b = blockIdx.x;
  int s = threadIdx.x;            // 512 threads
  __shared__ int cs[Sn];
  int sep = (ids[b * Sn + s] == SEP_ID) ? 1 : 0;
  cs[s] = sep;
  __syncthreads();
  for (int off = 1; off < Sn; off <<= 1) {
    int add = (s >= off) ? cs[s - off] : 0;
    __syncthreads();
    cs[s] += add;
    __syncthreads();
  }
  int csum = cs[s];
  int nb = cs[Sn - 1];
  int seg = csum - sep;
  bool valid = (!sep) && (s >= 1) && (seg < nb) && (seg < Mn);
  segv[b * Sn + s] = valid ? (unsigned char)seg : (unsigned char)0xFF;
  if (s == 0) nsep[b] = nb;
}

// ---------------- kernel 3: scores[b,s] = v . tanh(hidden @ W^T + bias)
// GEMM M=32768, N=768, K=768, single pass over N.
// Block: 512 thr = 8 waves (1M x 8N). Wave tile: 64 rows x 96 cols.
// A (hidden, fp32->bf16) double-buffered in LDS (stride 40 bf16, ~2-way banks).
// B (WB, bf16, L2-resident) loaded straight into frag registers, +1 prefetch.
__global__ __launch_bounds__(512) void score_gemm_kernel(
    const float* __restrict__ hid, const unsigned short* __restrict__ WB,
    const float* __restrict__ bbias, const float* __restrict__ vvec,
    float* __restrict__ scores) {
  __shared__ unsigned short As[2][64 * 40];   // [buf][row*40 + k], 80B row stride
  __shared__ float vLds[Hn];
  __shared__ float bLds[Hn];
  __shared__ float scpart[8][64];

  int t = threadIdx.x;
  size_t rowBase = (size_t)blockIdx.x * 64;
  int wid = t >> 6, lane = t & 63;
  int l15 = lane & 15, l4 = lane >> 4;
  int colBase = wid * 96;                     // wave-private 96-col slice

  for (int i = t; i < Hn; i += 512) { vLds[i] = vvec[i]; bLds[i] = bbias[i]; }

  // staging coords: each thread converts 4 floats of the 64x32 A tile
  const int srow = t >> 3;
  const int sk0 = (t & 7) * 4;
  const float* hrow = &hid[(rowBase + srow) * Hn + sk0];

  f32x4 acc[4][6];
#pragma unroll
  for (int mi = 0; mi < 4; ++mi)
#pragma unroll
    for (int ni = 0; ni < 6; ++ni) acc[mi][ni] = (f32x4){0.f, 0.f, 0.f, 0.f};

  bf16x8 bcur[6], bnxt[6];
  // prologue: stage A(k=0) into buf0, load B frags for k=0
  {
    float4 x = *reinterpret_cast<const float4*>(hrow);
    ushort4 u;
    u.x = f2bf(x.x); u.y = f2bf(x.y); u.z = f2bf(x.z); u.w = f2bf(x.w);
    *reinterpret_cast<ushort4*>(&As[0][srow * 40 + sk0]) = u;
  }
#pragma unroll
  for (int ni = 0; ni < 6; ++ni)
    bcur[ni] = *reinterpret_cast<const bf16x8*>(
        &WB[(size_t)(colBase + ni * 16 + l15) * Hn + l4 * 8]);
  __syncthreads();

  for (int kk = 0; kk < 24; ++kk) {
    const int buf = kk & 1;
    // A fragments for this K-step (LDS, broadcast across all 8 waves)
    bf16x8 af[4];
#pragma unroll
    for (int mi = 0; mi < 4; ++mi)
      af[mi] = *reinterpret_cast<const bf16x8*>(
          &As[buf][(mi * 16 + l15) * 40 + l4 * 8]);

    // prefetch k+1: B frags (L2) + A float4 (HBM) issued BEFORE the MFMAs
    float4 x;
    if (kk < 23) {
      const int kb = (kk + 1) * 32;
#pragma unroll
      for (int ni = 0; ni < 6; ++ni)
        bnxt[ni] = *reinterpret_cast<const bf16x8*>(
            &WB[(size_t)(colBase + ni * 16 + l15) * Hn + kb + l4 * 8]);
      x = *reinterpret_cast<const float4*>(hrow + kb);
    }

#pragma unroll
    for (int mi = 0; mi < 4; ++mi)
#pragma unroll
      for (int ni = 0; ni < 6; ++ni)
        acc[mi][ni] = __builtin_amdgcn_mfma_f32_16x16x32_bf16(
            af[mi], bcur[ni], acc[mi][ni], 0, 0, 0);

    if (kk < 23) {
      ushort4 u;
      u.x = f2bf(x.x); u.y = f2bf(x.y); u.z = f2bf(x.z); u.w = f2bf(x.w);
      *reinterpret_cast<ushort4*>(&As[buf ^ 1][srow * 40 + sk0]) = u;
#pragma unroll
      for (int ni = 0; ni < 6; ++ni) bcur[ni] = bnxt[ni];
    }
    __syncthreads();
  }

  // ---- fused epilogue: tanh(pre + b) * v, reduce over wave's 96 cols
  float sc[4][4];
#pragma unroll
  for (int mi = 0; mi < 4; ++mi)
#pragma unroll
    for (int r = 0; r < 4; ++r) sc[mi][r] = 0.f;
#pragma unroll
  for (int mi = 0; mi < 4; ++mi)
#pragma unroll
    for (int ni = 0; ni < 6; ++ni) {
      int col = colBase + ni * 16 + l15;
      float vv = vLds[col];
      float bb = bLds[col];
#pragma unroll
      for (int r = 0; r < 4; ++r)
        sc[mi][r] += tanh_fast(acc[mi][ni][r] + bb) * vv;
    }
  // reduce across the 16 col-lanes (lane bits 0..3)
#pragma unroll
  for (int off = 1; off < 16; off <<= 1)
#pragma unroll
    for (int mi = 0; mi < 4; ++mi)
#pragma unroll
      for (int r = 0; r < 4; ++r)
        sc[mi][r] += __shfl_xor(sc[mi][r], off, 64);
  if (l15 == 0) {
#pragma unroll
    for (int mi = 0; mi < 4; ++mi)
#pragma unroll
      for (int r = 0; r < 4; ++r)
        scpart[wid][mi * 16 + l4 * 4 + r] = sc[mi][r];
  }
  __syncthreads();
  if (t < 64) {
    float s = 0.f;
#pragma unroll
    for (int w = 0; w < 8; ++w) s += scpart[w][t];
    scores[rowBase + t] = s;
  }
}

// ---------------- kernel 4: per-(b,m) segment softmax + weighted pooling
__global__ __launch_bounds__(256) void pool_kernel(
    const float* __restrict__ hid, const float* __restrict__ scores,
    const unsigned char* __restrict__ segv, const int* __restrict__ nsep,
    float* __restrict__ out) {
  int bm = blockIdx.x;
  int b = bm / Mn, m = bm % Mn;
  int t = threadIdx.x;                      // 256 threads
  __shared__ float wLds[Sn];
  __shared__ float red[256];
  __shared__ int ired[256];
  const float NEG = -1e30f;

  int base = b * Sn;
  unsigned char mg = (unsigned char)m;
  unsigned char g0 = segv[base + t], g1 = segv[base + 256 + t];
  bool v0 = (g0 == mg), v1 = (g1 == mg);
  float s0 = v0 ? scores[base + t] : NEG;
  float s1 = v1 ? scores[base + 256 + t] : NEG;

  // block max
  red[t] = fmaxf(s0, s1);
  __syncthreads();
  for (int o = 128; o > 0; o >>= 1) {
    if (t < o) red[t] = fmaxf(red[t], red[t + o]);
    __syncthreads();
  }
  float gmax = red[0];
  __syncthreads();

  size_t obase = (size_t)bm * Hn;
  if (gmax <= -0.5e30f) {                    // empty segment
    int nb = nsep[b];
    float a0 = 0.f, a1 = 0.f, a2 = 0.f;
    if (m == 0 && nb == 0) {
      const float* hp = hid + (size_t)base * Hn;
      a0 = hp[t]; a1 = hp[t + 256]; a2 = hp[t + 512];
    }
    out[obase + t] = a0; out[obase + 256 + t] = a1; out[obase + 512 + t] = a2;
    return;
  }

  float e0 = v0 ? expf(s0 - gmax) : 0.f;
  float e1 = v1 ? expf(s1 - gmax) : 0.f;
  red[t] = e0 + e1;
  __syncthreads();
  for (int o = 128; o > 0; o >>= 1) {
    if (t < o) red[t] += red[t + o];
    __syncthreads();
  }
  float inv = 1.f / red[0];
  __syncthreads();
  wLds[t] = e0 * inv;
  wLds[256 + t] = e1 * inv;

  // segment position range (segments are contiguous runs)
  ired[t] = min(v0 ? t : 0x7fffffff, v1 ? (256 + t) : 0x7fffffff);
  __syncthreads();
  for (int o = 128; o > 0; o >>= 1) {
    if (t < o) ired[t] = min(ired[t], ired[t + o]);
    __syncthreads();
  }
  int start = ired[0];
  __syncthreads();
  ired[t] = max(v0 ? t : -1, v1 ? (256 + t) : -1);
  __syncthreads();
  for (int o = 128; o > 0; o >>= 1) {
    if (t < o) ired[t] = max(ired[t], ired[t + o]);
    __syncthreads();
  }
  int end = ired[0];
  __syncthreads();

  float a0 = 0.f, a1 = 0.f, a2 = 0.f;
  for (int s = start; s <= end; ++s) {
    float w = wLds[s];
    if (w != 0.f) {
      const float* hp = hid + (size_t)(base + s) * Hn;
      a0 += w * hp[t];
      a1 += w * hp[t + 256];
      a2 += w * hp[t + 512];
    }
  }
  out[obase + t] = a0;
  out[obase + 256 + t] = a1;
  out[obase + 512 + t] = a2;
}

// ---------------- launch
extern "C" void kernel_launch(void* const* d_in, const int* in_sizes, int n_in,
                              void* d_out, int out_size, void* d_ws, size_t ws_size,
                              hipStream_t stream) {
  const float* hidden = (const float*)d_in[0];
  const int* ids      = (const int*)d_in[1];
  const float* W      = (const float*)d_in[2];
  const float* bbias  = (const float*)d_in[3];
  const float* vvec   = (const float*)d_in[4];

  char* ws = (char*)d_ws;
  unsigned short* WB   = (unsigned short*)(ws);            // 1,179,648 B
  float* scores        = (float*)(ws + 1179648);           //   131,072 B
  unsigned char* segv  = (unsigned char*)(ws + 1310720);   //    32,768 B
  int* nsep            = (int*)(ws + 1343488);             //       256 B

  convw_kernel<<<576, 256, 0, stream>>>(W, WB);
  segscan_kernel<<<Bn, Sn, 0, stream>>>(ids, segv, nsep);
  score_gemm_kernel<<<BS / 64, 512, 0, stream>>>(hidden, WB, bbias, vvec, scores);
  pool_kernel<<<Bn * Mn, 256, 0, stream>>>(hidden, scores, segv, nsep, (float*)d_out);
}